// Round 1
// 151.137 us; speedup vs baseline: 1.0102x; 1.0102x over previous
//
#include <hip/hip_runtime.h>
#include <stdint.h>

#define NJ 19
#define ROOT_SCALE 200.0f
#define BLOCK 64           // one wave per block: 8 blocks/CU (LDS-bound), free barriers
#define ROWF 76            // floats per batch row (19 joints * 4)
#define ROWV 19            // float4s per batch row
// STRIDE == ROWF (76): LDS is a pure linear mirror of the block's global slab.
// 76 floats = 19 float4 slots; 19 odd => slot stride coprime with 8 bank-groups
// => conflict-free b128 access in every phase. Also enables global_load_lds.

struct Xform { float r[9]; float t[3]; };

__device__ __forceinline__ void quat_rt(float w, float x, float y, float z,
                                        float tx, float ty, float tz, Xform& o) {
    float ts = 2.0f / (w*w + x*x + y*y + z*z);
    o.r[0] = 1.0f - ts*(y*y + z*z); o.r[1] = ts*(x*y - z*w);        o.r[2] = ts*(x*z + y*w);
    o.r[3] = ts*(x*y + z*w);        o.r[4] = 1.0f - ts*(x*x + z*z); o.r[5] = ts*(y*z - x*w);
    o.r[6] = ts*(x*z - y*w);        o.r[7] = ts*(y*z + x*w);        o.r[8] = 1.0f - ts*(x*x + y*y);
    o.t[0] = o.r[0]*tx + o.r[1]*ty + o.r[2]*tz;
    o.t[1] = o.r[3]*tx + o.r[4]*ty + o.r[5]*tz;
    o.t[2] = o.r[6]*tx + o.r[7]*ty + o.r[8]*tz;
}

// o = p ∘ l  (rigid compose): o.r = p.r*l.r ; o.t = p.r*l.t + p.t
__device__ __forceinline__ void compose(const Xform& p, const Xform& l, Xform& o) {
#pragma unroll
    for (int i = 0; i < 3; ++i) {
        o.r[i*3+0] = p.r[i*3+0]*l.r[0] + p.r[i*3+1]*l.r[3] + p.r[i*3+2]*l.r[6];
        o.r[i*3+1] = p.r[i*3+0]*l.r[1] + p.r[i*3+1]*l.r[4] + p.r[i*3+2]*l.r[7];
        o.r[i*3+2] = p.r[i*3+0]*l.r[2] + p.r[i*3+1]*l.r[5] + p.r[i*3+2]*l.r[8];
        o.t[i]     = p.r[i*3+0]*l.t[0] + p.r[i*3+1]*l.t[1] + p.r[i*3+2]*l.t[2] + p.t[i];
    }
}

__global__ __launch_bounds__(BLOCK, 2) void fk_kernel(
    const float* __restrict__ root, const float* __restrict__ joint,
    const float* __restrict__ offs, float* __restrict__ out, int batch)
{
    __shared__ float s[BLOCK * ROWF];                     // 19456 B -> 8 blocks/CU
    const int tid = threadIdx.x;
    const int rowBase = blockIdx.x * BLOCK;               // first batch row of block
    const long long gbase = (long long)rowBase * ROWF;    // float offset into joint/out
    const int nvalid = min(BLOCK, batch - rowBase);       // valid rows this block

    // ---- stage joint rows: async global->LDS, 16B/lane, linear mirror ----
    if (nvalid == BLOCK) {
#pragma unroll
        for (int i = 0; i < ROWV; ++i) {
            // lane l of the (single) wave lands at LDS byte 16*(i*BLOCK) + l*16
            // == 16*v, exactly matching global float4 index v = i*BLOCK + tid.
            __builtin_amdgcn_global_load_lds(
                (const __attribute__((address_space(1))) uint32_t*)
                    (joint + gbase + (long long)(i * BLOCK + tid) * 4),
                (__attribute__((address_space(3))) uint32_t*)(s + i * BLOCK * 4),
                16, 0, 0);
        }
    } else {
        for (int v = tid; v < nvalid * ROWV; v += BLOCK) {
            *(float4*)(s + 4 * v) =
                *(const float4*)(joint + gbase + (long long)v * 4);
        }
    }
    __syncthreads();   // drains vmcnt for the global_load_lds

    // ---- per-thread FK chain; results overwrite quats in own LDS row ----
    if (tid < nvalid) {
        float* row = s + tid * ROWF;
        const int b = rowBase + tid;
        const float rx = root[(long long)b*3 + 0] * ROOT_SCALE;
        const float ry = root[(long long)b*3 + 1] * ROOT_SCALE;
        const float rz = root[(long long)b*3 + 2] * ROOT_SCALE;

        Xform cur, sv0, sv2, loc;
#pragma unroll
        for (int j = 0; j < NJ; ++j) {
            float4 q = *(const float4*)(&row[j*4]);       // (w,x,y,z)
            float tx = offs[j*16 + 3], ty = offs[j*16 + 7], tz = offs[j*16 + 11];
            quat_rt(q.x, q.y, q.z, q.w, tx, ty, tz, loc);
            if (j == 0) {
                cur = loc;
            } else {
                Xform nxt;
                if (j == 5 || j == 9)        compose(sv2, loc, nxt);   // parent = joint 2
                else if (j == 13 || j == 16) compose(sv0, loc, nxt);   // parent = joint 0
                else                         compose(cur, loc, nxt);   // parent = j-1
                cur = nxt;
            }
            if (j == 0) sv0 = cur;
            if (j == 2) sv2 = cur;
            float4 o;
            o.x = cur.t[0] + rx;
            o.y = cur.t[1] + ry;
            o.z = cur.t[2] + rz;
            o.w = 1.0f;                                   // M[3][3] exactly
            *(float4*)(&row[j*4]) = o;
        }
    }
    __syncthreads();

    // ---- coalesced float4 writeback: LDS is a linear mirror, no div/mod ----
    if (nvalid == BLOCK) {
#pragma unroll
        for (int i = 0; i < ROWV; ++i) {
            int v = i * BLOCK + tid;
            *(float4*)(out + gbase + (long long)v * 4) = *(const float4*)(s + 4 * v);
        }
    } else {
        for (int v = tid; v < nvalid * ROWV; v += BLOCK) {
            *(float4*)(out + gbase + (long long)v * 4) = *(const float4*)(s + 4 * v);
        }
    }
}

extern "C" void kernel_launch(void* const* d_in, const int* in_sizes, int n_in,
                              void* d_out, int out_size, void* d_ws, size_t ws_size,
                              hipStream_t stream) {
    const float* root  = (const float*)d_in[0];  // (B,3)
    const float* joint = (const float*)d_in[1];  // (B,76)
    const float* offs  = (const float*)d_in[2];  // (19,4,4)
    float* out = (float*)d_out;                  // (B,19,4)
    const int batch = in_sizes[1] / ROWF;
    const int grid = (batch + BLOCK - 1) / BLOCK;
    fk_kernel<<<grid, BLOCK, 0, stream>>>(root, joint, offs, out, batch);
}